// Round 1
// baseline (21027.887 us; speedup 1.0000x reference)
//
#include <hip/hip_runtime.h>
#include <hip/hip_bf16.h>
#include <hip/hip_cooperative_groups.h>

namespace cg = cooperative_groups;

#define T_STEPS 512
#define INP     512
#define NB      256
#define HID     1024
#define WID     512
#define KZ      1536   // HID + INP

typedef short          bf16x8   __attribute__((ext_vector_type(8)));
typedef float          f32x4    __attribute__((ext_vector_type(4)));
typedef unsigned short ushort8  __attribute__((ext_vector_type(8)));
typedef unsigned short ushort4v __attribute__((ext_vector_type(4)));

__device__ __forceinline__ unsigned short f2bf(float x) {
  __hip_bfloat16 h = __float2bfloat16(x);
  return __builtin_bit_cast(unsigned short, h);
}
__device__ __forceinline__ float sigm(float x) { return 1.0f / (1.0f + __expf(-x)); }

// ---------------- setup: bf16 weight conversion + zT[0] init ----------------
__global__ void elman_setup(const float* __restrict__ W_h, const float* __restrict__ W_y,
                            const float* __restrict__ h0, const float* __restrict__ xs,
                            unsigned short* __restrict__ Whb, unsigned short* __restrict__ Wyb,
                            unsigned short* __restrict__ zT) {
  const int NT1 = HID * KZ;     // W_h elems
  const int NT2 = WID * HID;    // W_y elems
  const int NT3 = NB * HID;     // h0 tiled into zT[0]
  const int NT4 = NB * INP;     // x_0 transposed into zT[0]
  const int TOT = NT1 + NT2 + NT3 + NT4;
  for (int i = blockIdx.x * blockDim.x + threadIdx.x; i < TOT; i += gridDim.x * blockDim.x) {
    if (i < NT1) {
      Whb[i] = f2bf(W_h[i]);
    } else if (i < NT1 + NT2) {
      const int j = i - NT1;
      Wyb[j] = f2bf(W_y[j]);
    } else if (i < NT1 + NT2 + NT3) {
      const int j = i - NT1 - NT2;
      const int b = j >> 10, m = j & (HID - 1);
      zT[(size_t)b * KZ + m] = f2bf(h0[m]);
    } else {
      const int j = i - NT1 - NT2 - NT3;
      const int b = j & (NB - 1), ii = j >> 8;
      zT[(size_t)b * KZ + HID + ii] = f2bf(xs[(size_t)ii * NB + b]);
    }
  }
}

// ---------------- shared memory ----------------
union SMem {
  struct { unsigned short A[64 * 72]; unsigned short B[32 * 72]; } g;  // padded stride 72 (bank-safe)
  float xt[64 * 65];                                                    // x transpose tile
};

// 64(M)x32(N) tile GEMM, K staged in chunks of 64, 4 waves (2x2), 16x16x32 bf16 MFMA.
// A: row-major [.,lda] bf16; B: zT col-major (col stride KZ) bf16.
template <int KITERS>
__device__ __forceinline__ void tile_gemm(const unsigned short* __restrict__ A, int lda,
                                          const unsigned short* __restrict__ B,
                                          SMem& sm, int tid, f32x4& acc0, f32x4& acc1) {
  const int lane = tid & 63;
  const int wave = tid >> 6;
  const int wm = wave >> 1, wn = wave & 1;
  const int lr = lane & 15, lk = lane >> 4;
  const unsigned short* Ab = A + (size_t)(tid >> 2) * lda + (tid & 3) * 8;
  const unsigned short* Bb = B + (size_t)(tid >> 3) * KZ  + (tid & 7) * 8;
  const int arow = (tid >> 2) * 72 + (tid & 3) * 8;
  const int brow = (tid >> 3) * 72 + (tid & 7) * 8;
  const int afr0 = (wm * 32 + lr) * 72 + lk * 8;
  const int afr1 = (wm * 32 + 16 + lr) * 72 + lk * 8;
  const int bfr  = (wn * 16 + lr) * 72 + lk * 8;
  for (int kk = 0; kk < KITERS; ++kk) {
    const int k0 = kk * 64;
    ushort8 av0 = *(const ushort8*)(Ab + k0);
    ushort8 av1 = *(const ushort8*)(Ab + k0 + 32);
    ushort8 bv  = *(const ushort8*)(Bb + k0);
    __syncthreads();  // previous chunk's frag reads complete
    *(ushort8*)&sm.g.A[arow]      = av0;
    *(ushort8*)&sm.g.A[arow + 32] = av1;
    *(ushort8*)&sm.g.B[brow]      = bv;
    __syncthreads();
#pragma unroll
    for (int s = 0; s < 2; ++s) {
      bf16x8 a0 = *(const bf16x8*)&sm.g.A[afr0 + s * 32];
      bf16x8 a1 = *(const bf16x8*)&sm.g.A[afr1 + s * 32];
      bf16x8 b  = *(const bf16x8*)&sm.g.B[bfr  + s * 32];
      acc0 = __builtin_amdgcn_mfma_f32_16x16x32_bf16(a0, b, acc0, 0, 0, 0);
      acc1 = __builtin_amdgcn_mfma_f32_16x16x32_bf16(a1, b, acc1, 0, 0, 0);
    }
  }
}

// ---------------- persistent sequential kernel ----------------
// Phase t (t=0..T):
//   WGs   0..127 : h_{t+1} = sigm(W_h @ z_t + b_h)           -> zT[(t+1)&1] rows 0..1023   (t < T)
//   WGs 128..191 : y_{t-1} = sigm(W_y @ h_t + b_y)           -> out[t-1]                   (t >= 1)
//   WGs 192..223 : transpose x_{t+1}                         -> zT[(t+1)&1] rows 1024..1535 (t < T-1)
//   grid.sync()
__global__ void __launch_bounds__(256, 1) elman_seq(
    const float* __restrict__ xs, const float* __restrict__ bh,
    const float* __restrict__ by, const unsigned short* __restrict__ Whb,
    const unsigned short* __restrict__ Wyb, unsigned short* __restrict__ zT,
    float* __restrict__ out) {
  cg::grid_group grid = cg::this_grid();
  __shared__ SMem sm;
  const int wg = blockIdx.x;
  const int tid = threadIdx.x;
  const int lane = tid & 63;
  const int wave = tid >> 6;
  const int wm = wave >> 1, wn = wave & 1;

  for (int t = 0; t <= T_STEPS; ++t) {
    const unsigned short* zc = zT + (size_t)(t & 1) * (NB * KZ);
    unsigned short* zn = zT + (size_t)((t + 1) & 1) * (NB * KZ);

    if (wg < 128) {
      if (t < T_STEPS) {
        const int m0 = (wg & 15) * 64;   // wg&7 -> XCD gets fixed m-slice (L2 locality)
        const int n0 = (wg >> 4) * 32;
        f32x4 acc0 = {0.f, 0.f, 0.f, 0.f}, acc1 = {0.f, 0.f, 0.f, 0.f};
        tile_gemm<KZ / 64>(Whb + (size_t)m0 * KZ, KZ, zc + (size_t)n0 * KZ, sm, tid, acc0, acc1);
        const int ccol = n0 + wn * 16 + (lane & 15);
        unsigned short* zrow = zn + (size_t)ccol * KZ;
#pragma unroll
        for (int f = 0; f < 2; ++f) {
          const int crow = m0 + wm * 32 + f * 16 + (lane >> 4) * 4;
          const f32x4 acc = f ? acc1 : acc0;
          const f32x4 bias = *(const f32x4*)&bh[crow];
          ushort4v o;
#pragma unroll
          for (int r = 0; r < 4; ++r) o[r] = f2bf(sigm(acc[r] + bias[r]));
          *(ushort4v*)(zrow + crow) = o;
        }
      }
    } else if (wg < 192) {
      if (t >= 1) {
        const int idx = wg - 128;
        const int m0 = (idx & 7) * 64;
        const int n0 = (idx >> 3) * 32;
        f32x4 acc0 = {0.f, 0.f, 0.f, 0.f}, acc1 = {0.f, 0.f, 0.f, 0.f};
        tile_gemm<HID / 64>(Wyb + (size_t)m0 * HID, HID, zc + (size_t)n0 * KZ, sm, tid, acc0, acc1);
        float* op = out + (size_t)(t - 1) * (WID * NB);
        const int ccol = n0 + wn * 16 + (lane & 15);
#pragma unroll
        for (int f = 0; f < 2; ++f) {
          const int crow = m0 + wm * 32 + f * 16 + (lane >> 4) * 4;
          const f32x4 acc = f ? acc1 : acc0;
          const f32x4 bias = *(const f32x4*)&by[crow];
#pragma unroll
          for (int r = 0; r < 4; ++r)
            op[(size_t)(crow + r) * NB + ccol] = sigm(acc[r] + bias[r]);
        }
      }
    } else {
      if (t < T_STEPS - 1) {
        const int idx = wg - 192;
        const int i0 = (idx & 7) * 64;
        const int b0 = (idx >> 3) * 64;
        const float* xp = xs + (size_t)(t + 1) * (INP * NB);
#pragma unroll 4
        for (int r = 0; r < 16; ++r) {
          const int il = r * 4 + (tid >> 6);
          sm.xt[il * 65 + (tid & 63)] = xp[(size_t)(i0 + il) * NB + b0 + (tid & 63)];
        }
        __syncthreads();
        const int bl = tid >> 2;
        unsigned short* zx = zn + (size_t)(b0 + bl) * KZ + HID + i0;
#pragma unroll
        for (int c0 = 0; c0 < 2; ++c0) {
          const int c = (tid & 3) + c0 * 4;
          ushort8 o;
#pragma unroll
          for (int e = 0; e < 8; ++e) o[e] = f2bf(sm.xt[(c * 8 + e) * 65 + bl]);
          *(ushort8*)(zx + c * 8) = o;
        }
      }
    }
    grid.sync();
  }
}

// ---------------- host launch ----------------
extern "C" void kernel_launch(void* const* d_in, const int* in_sizes, int n_in,
                              void* d_out, int out_size, void* d_ws, size_t ws_size,
                              hipStream_t stream) {
  const float* xs  = (const float*)d_in[0];
  const float* W_h = (const float*)d_in[1];
  const float* b_h = (const float*)d_in[2];
  const float* W_y = (const float*)d_in[3];
  const float* b_y = (const float*)d_in[4];
  const float* h0  = (const float*)d_in[5];
  float* out = (float*)d_out;

  // ws layout: Whb bf16 [1024][1536] | Wyb bf16 [512][1024] | zT bf16 [2][256][1536]
  unsigned short* Whb = (unsigned short*)d_ws;
  unsigned short* Wyb = Whb + (size_t)HID * KZ;
  unsigned short* zT  = Wyb + (size_t)WID * HID;

  elman_setup<<<dim3(1024), dim3(256), 0, stream>>>(W_h, W_y, h0, xs, Whb, Wyb, zT);

  void* args[7];
  args[0] = (void*)&xs;  args[1] = (void*)&b_h; args[2] = (void*)&b_y;
  args[3] = (void*)&Whb; args[4] = (void*)&Wyb; args[5] = (void*)&zT;
  args[6] = (void*)&out;
  hipLaunchCooperativeKernel((void*)elman_seq, dim3(224), dim3(256), args, 0u, stream);
}

// Round 2
// 18704.836 us; speedup vs baseline: 1.1242x; 1.1242x over previous
//
#include <hip/hip_runtime.h>
#include <hip/hip_bf16.h>
#include <hip/hip_cooperative_groups.h>

namespace cg = cooperative_groups;

#define T_STEPS 512
#define INP     512
#define NB      256
#define HID     1024
#define WID     512
#define KZ      1536   // HID + INP
#define ZSZ     (NB * KZ)

typedef short          bf16x8   __attribute__((ext_vector_type(8)));
typedef float          f32x4    __attribute__((ext_vector_type(4)));
typedef float          f32x2    __attribute__((ext_vector_type(2)));
typedef unsigned short ushort8  __attribute__((ext_vector_type(8)));
typedef unsigned short ushort2v __attribute__((ext_vector_type(2)));
typedef unsigned short ushort4v __attribute__((ext_vector_type(4)));

__device__ __forceinline__ unsigned short f2bf(float x) {
  __hip_bfloat16 h = __float2bfloat16(x);
  return __builtin_bit_cast(unsigned short, h);
}
__device__ __forceinline__ float sigm(float x) { return 1.0f / (1.0f + __expf(-x)); }

// ---------------- setup: init z[0] = [h0 tiled ; x_0 transposed] ----------------
__global__ void elman_setup(const float* __restrict__ h0, const float* __restrict__ xs,
                            unsigned short* __restrict__ zT) {
  const int b = blockIdx.x;   // batch column 0..255
  for (int k = threadIdx.x; k < KZ; k += blockDim.x) {
    const float v = (k < HID) ? h0[k] : xs[(size_t)(k - HID) * NB + b];
    zT[(size_t)b * KZ + k] = f2bf(v);
  }
}

// LDS partial-sum buffer: 8 waves x [32 cols][stride 36 words (32 rows + 4 pad)]
// stride 36 words = 9 x 16B-granules (odd) -> even 8-lanes/granule on b128 writes
// and even 4-lanes/granule on b64 reads (optimal, conflict-free).
#define PSTR 36
#define PWSZ (32 * PSTR)   // 1152 words / wave;  8 waves = 36 KiB total

// ---------------- persistent sequential kernel ----------------
// 256 WGs x 512 threads (8 waves), 1 WG/CU.
//   WGs   0..127 : h_{t+1} = sigm(Wh @ z_t + bh)   (t < T)      tile 64m x 32n, K-split 8
//   WGs 128..191 : y_{t-1} = sigm(Wy @ h_t + by)   (t >= 1)     tile 64m x 32n, K-split 8
//   WGs 192..255 : transpose x_{t+1} -> z_{t+1}    (t < T-1)
// Weights live in VGPRs for the whole loop (immune to grid.sync L2 invalidation).
__global__ void __launch_bounds__(512, 2) elman_seq(
    const float* __restrict__ xs,
    const float* __restrict__ Wh, const float* __restrict__ bh,
    const float* __restrict__ Wy, const float* __restrict__ by,
    unsigned short* __restrict__ zT, float* __restrict__ out) {
  cg::grid_group grid = cg::this_grid();
  __shared__ float P[8 * PWSZ];
  const int wg = blockIdx.x, tid = threadIdx.x;
  const int w = tid >> 6, lane = tid & 63;
  const int lr = lane & 15, lk = lane >> 4;

  if (wg < 128) {
    // ================= h role =================
    const int m0 = (wg >> 3) * 64;          // 16 m-slices
    const int n0 = (wg & 7) * 32;           // wg&7 -> XCD keyed to batch slice (L2 locality)
    const int kw = w * 192;                 // this wave's K-slice (6 chunks of 32)
    bf16x8 A[4][6];                         // resident W_h fragments: 96 VGPRs
#pragma unroll
    for (int mt = 0; mt < 4; ++mt)
#pragma unroll
      for (int kc = 0; kc < 6; ++kc) {
        const float* wp = Wh + (size_t)(m0 + mt * 16 + lr) * KZ + kw + kc * 32 + lk * 8;
        const f32x4 f0 = *(const f32x4*)wp;
        const f32x4 f1 = *(const f32x4*)(wp + 4);
        ushort8 a;
#pragma unroll
        for (int e = 0; e < 4; ++e) { a[e] = f2bf(f0[e]); a[4 + e] = f2bf(f1[e]); }
        A[mt][kc] = __builtin_bit_cast(bf16x8, a);
      }
    const int lcol = tid >> 4;              // reduction role: col 0..31
    const int r2 = (tid & 15) * 2;          // row pair within 32-row half
    f32x2 bias[2];
#pragma unroll
    for (int hf = 0; hf < 2; ++hf) bias[hf] = *(const f32x2*)&bh[m0 + hf * 32 + r2];
    float* Pw = P + w * PWSZ;

    for (int t = 0; t <= T_STEPS; ++t) {
      const unsigned short* zc = zT + (size_t)(t & 1) * ZSZ;
      unsigned short* zn = zT + (size_t)((t + 1) & 1) * ZSZ;
      if (t < T_STEPS) {
        const unsigned short* zb = zc + (size_t)(n0 + lr) * KZ + kw + lk * 8;
        f32x4 acc[4][2];
#pragma unroll
        for (int mt = 0; mt < 4; ++mt)
#pragma unroll
          for (int nt = 0; nt < 2; ++nt) acc[mt][nt] = (f32x4){0.f, 0.f, 0.f, 0.f};
#pragma unroll
        for (int kc = 0; kc < 6; ++kc)
#pragma unroll
          for (int nt = 0; nt < 2; ++nt) {
            const bf16x8 b = *(const bf16x8*)(zb + nt * (16 * KZ) + kc * 32);
#pragma unroll
            for (int mt = 0; mt < 4; ++mt)
              acc[mt][nt] = __builtin_amdgcn_mfma_f32_16x16x32_bf16(A[mt][kc], b, acc[mt][nt], 0, 0, 0);
          }
        // two-pass cross-wave K reduction (32-row halves) through 36 KiB LDS
#pragma unroll
        for (int hf = 0; hf < 2; ++hf) {
#pragma unroll
          for (int mp = 0; mp < 2; ++mp) {
            const int mt = hf * 2 + mp;
#pragma unroll
            for (int nt = 0; nt < 2; ++nt)
              *(f32x4*)&Pw[(nt * 16 + lr) * PSTR + mp * 16 + lk * 4] = acc[mt][nt];
          }
          __syncthreads();
          f32x2 s = {0.f, 0.f};
#pragma unroll
          for (int ww = 0; ww < 8; ++ww)
            s += *(const f32x2*)&P[ww * PWSZ + lcol * PSTR + r2];
          s += bias[hf];
          ushort2v o2;
          o2[0] = f2bf(sigm(s[0]));
          o2[1] = f2bf(sigm(s[1]));
          *(ushort2v*)(zn + (size_t)(n0 + lcol) * KZ + m0 + hf * 32 + r2) = o2;
          if (hf == 0) __syncthreads();   // reads done before pass-2 writes
        }
      }
      grid.sync();
    }

  } else if (wg < 192) {
    // ================= y role =================
    const int idx = wg - 128;
    const int m0 = (idx >> 3) * 64;         // 8 m-slices
    const int n0 = (idx & 7) * 32;          // same col-slice per XCD as h role
    const int kw = w * 128;                 // K-slice: 4 chunks of 32 (K = HID)
    bf16x8 A[4][4];                         // resident W_y fragments: 64 VGPRs
#pragma unroll
    for (int mt = 0; mt < 4; ++mt)
#pragma unroll
      for (int kc = 0; kc < 4; ++kc) {
        const float* wp = Wy + (size_t)(m0 + mt * 16 + lr) * HID + kw + kc * 32 + lk * 8;
        const f32x4 f0 = *(const f32x4*)wp;
        const f32x4 f1 = *(const f32x4*)(wp + 4);
        ushort8 a;
#pragma unroll
        for (int e = 0; e < 4; ++e) { a[e] = f2bf(f0[e]); a[4 + e] = f2bf(f1[e]); }
        A[mt][kc] = __builtin_bit_cast(bf16x8, a);
      }
    const int lcol = tid & 31;              // reduction role: col (coalesced f32 stores)
    const int r2 = (tid >> 5) * 2;          // row pair within 32-row half
    f32x2 bias[2];
#pragma unroll
    for (int hf = 0; hf < 2; ++hf) bias[hf] = *(const f32x2*)&by[m0 + hf * 32 + r2];
    float* Pw = P + w * PWSZ;

    for (int t = 0; t <= T_STEPS; ++t) {
      const unsigned short* zc = zT + (size_t)(t & 1) * ZSZ;
      if (t >= 1) {
        const unsigned short* zb = zc + (size_t)(n0 + lr) * KZ + kw + lk * 8;
        f32x4 acc[4][2];
#pragma unroll
        for (int mt = 0; mt < 4; ++mt)
#pragma unroll
          for (int nt = 0; nt < 2; ++nt) acc[mt][nt] = (f32x4){0.f, 0.f, 0.f, 0.f};
#pragma unroll
        for (int kc = 0; kc < 4; ++kc)
#pragma unroll
          for (int nt = 0; nt < 2; ++nt) {
            const bf16x8 b = *(const bf16x8*)(zb + nt * (16 * KZ) + kc * 32);
#pragma unroll
            for (int mt = 0; mt < 4; ++mt)
              acc[mt][nt] = __builtin_amdgcn_mfma_f32_16x16x32_bf16(A[mt][kc], b, acc[mt][nt], 0, 0, 0);
          }
        float* op = out + (size_t)(t - 1) * (WID * NB);
#pragma unroll
        for (int hf = 0; hf < 2; ++hf) {
#pragma unroll
          for (int mp = 0; mp < 2; ++mp) {
            const int mt = hf * 2 + mp;
#pragma unroll
            for (int nt = 0; nt < 2; ++nt)
              *(f32x4*)&Pw[(nt * 16 + lr) * PSTR + mp * 16 + lk * 4] = acc[mt][nt];
          }
          __syncthreads();
          f32x2 s = {0.f, 0.f};
#pragma unroll
          for (int ww = 0; ww < 8; ++ww)
            s += *(const f32x2*)&P[ww * PWSZ + lcol * PSTR + r2];
          s += bias[hf];
          const int row = m0 + hf * 32 + r2;
          op[(size_t)(row + 0) * NB + n0 + lcol] = sigm(s[0]);
          op[(size_t)(row + 1) * NB + n0 + lcol] = sigm(s[1]);
          if (hf == 0) __syncthreads();
        }
      }
      grid.sync();
    }

  } else {
    // ================= x-transpose role =================
    const int xi = wg - 192;                // 0..63
    const int i0 = (xi >> 3) * 64;          // input-feature block
    const int b0 = (xi & 7) * 32;           // batch block
    const int c = tid & 31, rb = tid >> 5;  // col within block, row-quad 0..15
    for (int t = 0; t <= T_STEPS; ++t) {
      unsigned short* zn = zT + (size_t)((t + 1) & 1) * ZSZ;
      if (t < T_STEPS - 1) {
        const float* xp = xs + (size_t)(t + 1) * (INP * NB) + (size_t)(i0 + rb * 4) * NB + b0 + c;
        ushort4v o;
#pragma unroll
        for (int j = 0; j < 4; ++j) o[j] = f2bf(xp[(size_t)j * NB]);
        *(ushort4v*)(zn + (size_t)(b0 + c) * KZ + HID + i0 + rb * 4) = o;
      }
      grid.sync();
    }
  }
}

// ---------------- host launch ----------------
extern "C" void kernel_launch(void* const* d_in, const int* in_sizes, int n_in,
                              void* d_out, int out_size, void* d_ws, size_t ws_size,
                              hipStream_t stream) {
  (void)in_sizes; (void)n_in; (void)out_size; (void)ws_size;
  const float* xs  = (const float*)d_in[0];
  const float* W_h = (const float*)d_in[1];
  const float* b_h = (const float*)d_in[2];
  const float* W_y = (const float*)d_in[3];
  const float* b_y = (const float*)d_in[4];
  const float* h0  = (const float*)d_in[5];
  float* out = (float*)d_out;

  // ws layout: zT bf16 [2][256][1536] only (weights live in registers)
  unsigned short* zT = (unsigned short*)d_ws;

  elman_setup<<<dim3(NB), dim3(256), 0, stream>>>(h0, xs, zT);

  void* args[7];
  args[0] = (void*)&xs;  args[1] = (void*)&W_h; args[2] = (void*)&b_h;
  args[3] = (void*)&W_y; args[4] = (void*)&b_y; args[5] = (void*)&zT;
  args[6] = (void*)&out;
  hipLaunchCooperativeKernel((void*)elman_seq, dim3(256), dim3(512), args, 0u, stream);
}

// Round 3
// 8211.925 us; speedup vs baseline: 2.5607x; 2.2778x over previous
//
#include <hip/hip_runtime.h>
#include <hip/hip_bf16.h>

#define T_STEPS 512
#define INP     512
#define NB      256
#define HID     1024
#define WID     512
#define KZ      1536   // HID + INP
#define ZSZ     (NB * KZ)

typedef short          bf16x8   __attribute__((ext_vector_type(8)));
typedef float          f32x4    __attribute__((ext_vector_type(4)));
typedef float          f32x2    __attribute__((ext_vector_type(2)));
typedef unsigned short ushort8  __attribute__((ext_vector_type(8)));
typedef unsigned short ushort2v __attribute__((ext_vector_type(2)));
typedef unsigned short ushort4v __attribute__((ext_vector_type(4)));

__device__ __forceinline__ unsigned short f2bf(float x) {
  __hip_bfloat16 h = __float2bfloat16(x);
  return __builtin_bit_cast(unsigned short, h);
}
__device__ __forceinline__ float sigm(float x) { return 1.0f / (1.0f + __expf(-x)); }

// ---------------- setup: init z[0] = [h0 tiled ; x_0 transposed], zero barriers ----------
__global__ void elman_setup(const float* __restrict__ h0, const float* __restrict__ xs,
                            unsigned short* __restrict__ zT, unsigned* __restrict__ bars) {
  const int b = blockIdx.x;   // batch column 0..255
  if (b == 0) {
    for (int j = threadIdx.x; j < 512; j += blockDim.x) bars[j] = 0u;
  }
  for (int k = threadIdx.x; k < KZ; k += blockDim.x) {
    const float v = (k < HID) ? h0[k] : xs[(size_t)(k - HID) * NB + b];
    zT[(size_t)b * KZ + k] = f2bf(v);
  }
}

// ---------------- per-slice ticket barrier ----------------
// Slices (batch 32-col groups) never exchange data; 32 WGs per slice sync among
// themselves only. Monotonic counter, one cacheline per slice. Thread 0:
// release-fence -> arrive -> spin (relaxed agent loads, s_sleep) -> acquire-fence.
__device__ __forceinline__ void slice_bar(unsigned* bar, unsigned tgt) {
  __syncthreads();                 // all waves' work done & stores issued
  if (threadIdx.x == 0) {
    __threadfence();               // release: publish z writes (L2 -> coherence point)
    atomicAdd(bar, 1u);            // device-scope RMW
    while (__hip_atomic_load(bar, __ATOMIC_RELAXED, __HIP_MEMORY_SCOPE_AGENT) < tgt)
      __builtin_amdgcn_s_sleep(1);
    __threadfence();               // acquire: invalidate stale L1/L2 lines
  }
  __syncthreads();                 // whole WG released, loads ordered after acquire
}

// LDS partial-sum buffer: 8 waves x [32 cols][stride 36 words (32 rows + 4 pad)]
#define PSTR 36
#define PWSZ (32 * PSTR)

// ---------------- persistent sequential kernel ----------------
// 256 WGs x 512 threads (8 waves), 1 WG/CU. slice = wg & 7 (XCD-local group of 32 WGs):
//   16 h-WGs : h_{t+1} = sigm(Wh @ z_t + bh)   (t < T)      tile 64m x 32n, K-split 8
//    8 y-WGs : y_{t-1} = sigm(Wy @ h_t + by)   (t >= 1)     tile 64m x 32n, K-split 8
//    8 x-WGs : transpose x_{t+1} -> z_{t+1}    (t < T-1)
// Weights live in VGPRs for the whole loop.
__global__ void __launch_bounds__(512, 2) elman_seq(
    const float* __restrict__ xs,
    const float* __restrict__ Wh, const float* __restrict__ bh,
    const float* __restrict__ Wy, const float* __restrict__ by,
    unsigned short* __restrict__ zT, float* __restrict__ out,
    unsigned* __restrict__ bars) {
  __shared__ float P[8 * PWSZ];
  const int wg = blockIdx.x, tid = threadIdx.x;
  const int w = tid >> 6, lane = tid & 63;
  const int lr = lane & 15, lk = lane >> 4;
  unsigned* bar = bars + (wg & 7) * 64;    // one cacheline per slice

  if (wg < 128) {
    // ================= h role =================
    const int m0 = (wg >> 3) * 64;          // 16 m-slices
    const int n0 = (wg & 7) * 32;           // slice = XCD-keyed batch columns
    const int kw = w * 192;                 // this wave's K-slice (6 chunks of 32)
    bf16x8 A[4][6];                         // resident W_h fragments: 96 VGPRs
#pragma unroll
    for (int mt = 0; mt < 4; ++mt)
#pragma unroll
      for (int kc = 0; kc < 6; ++kc) {
        const float* wp = Wh + (size_t)(m0 + mt * 16 + lr) * KZ + kw + kc * 32 + lk * 8;
        const f32x4 f0 = *(const f32x4*)wp;
        const f32x4 f1 = *(const f32x4*)(wp + 4);
        ushort8 a;
#pragma unroll
        for (int e = 0; e < 4; ++e) { a[e] = f2bf(f0[e]); a[4 + e] = f2bf(f1[e]); }
        A[mt][kc] = __builtin_bit_cast(bf16x8, a);
      }
    const int lcol = tid >> 4;              // reduction role: col 0..31
    const int r2 = (tid & 15) * 2;          // row pair within 32-row half
    f32x2 bias[2];
#pragma unroll
    for (int hf = 0; hf < 2; ++hf) bias[hf] = *(const f32x2*)&bh[m0 + hf * 32 + r2];
    float* Pw = P + w * PWSZ;

    for (int t = 0; t <= T_STEPS; ++t) {
      const unsigned short* zc = zT + (size_t)(t & 1) * ZSZ;
      unsigned short* zn = zT + (size_t)((t + 1) & 1) * ZSZ;
      if (t < T_STEPS) {
        const unsigned short* zb = zc + (size_t)(n0 + lr) * KZ + kw + lk * 8;
        f32x4 acc[4][2];
#pragma unroll
        for (int mt = 0; mt < 4; ++mt)
#pragma unroll
          for (int nt = 0; nt < 2; ++nt) acc[mt][nt] = (f32x4){0.f, 0.f, 0.f, 0.f};
#pragma unroll
        for (int kc = 0; kc < 6; ++kc)
#pragma unroll
          for (int nt = 0; nt < 2; ++nt) {
            const bf16x8 b = *(const bf16x8*)(zb + nt * (16 * KZ) + kc * 32);
#pragma unroll
            for (int mt = 0; mt < 4; ++mt)
              acc[mt][nt] = __builtin_amdgcn_mfma_f32_16x16x32_bf16(A[mt][kc], b, acc[mt][nt], 0, 0, 0);
          }
        // two-pass cross-wave K reduction (32-row halves) through 36 KiB LDS
#pragma unroll
        for (int hf = 0; hf < 2; ++hf) {
#pragma unroll
          for (int mp = 0; mp < 2; ++mp) {
            const int mt = hf * 2 + mp;
#pragma unroll
            for (int nt = 0; nt < 2; ++nt)
              *(f32x4*)&Pw[(nt * 16 + lr) * PSTR + mp * 16 + lk * 4] = acc[mt][nt];
          }
          __syncthreads();
          f32x2 s = {0.f, 0.f};
#pragma unroll
          for (int ww = 0; ww < 8; ++ww)
            s += *(const f32x2*)&P[ww * PWSZ + lcol * PSTR + r2];
          s += bias[hf];
          ushort2v o2;
          o2[0] = f2bf(sigm(s[0]));
          o2[1] = f2bf(sigm(s[1]));
          *(ushort2v*)(zn + (size_t)(n0 + lcol) * KZ + m0 + hf * 32 + r2) = o2;
          if (hf == 0) __syncthreads();   // reads done before pass-2 writes
        }
      }
      slice_bar(bar, 32u * (unsigned)(t + 1));
    }

  } else if (wg < 192) {
    // ================= y role =================
    const int idx = wg - 128;
    const int m0 = (idx >> 3) * 64;         // 8 m-slices
    const int n0 = (idx & 7) * 32;          // same slice as h role (wg&7 preserved)
    const int kw = w * 128;                 // K-slice: 4 chunks of 32 (K = HID)
    bf16x8 A[4][4];                         // resident W_y fragments: 64 VGPRs
#pragma unroll
    for (int mt = 0; mt < 4; ++mt)
#pragma unroll
      for (int kc = 0; kc < 4; ++kc) {
        const float* wp = Wy + (size_t)(m0 + mt * 16 + lr) * HID + kw + kc * 32 + lk * 8;
        const f32x4 f0 = *(const f32x4*)wp;
        const f32x4 f1 = *(const f32x4*)(wp + 4);
        ushort8 a;
#pragma unroll
        for (int e = 0; e < 4; ++e) { a[e] = f2bf(f0[e]); a[4 + e] = f2bf(f1[e]); }
        A[mt][kc] = __builtin_bit_cast(bf16x8, a);
      }
    const int lcol = tid & 31;              // reduction role: col (coalesced f32 stores)
    const int r2 = (tid >> 5) * 2;          // row pair within 32-row half
    f32x2 bias[2];
#pragma unroll
    for (int hf = 0; hf < 2; ++hf) bias[hf] = *(const f32x2*)&by[m0 + hf * 32 + r2];
    float* Pw = P + w * PWSZ;

    for (int t = 0; t <= T_STEPS; ++t) {
      const unsigned short* zc = zT + (size_t)(t & 1) * ZSZ;
      if (t >= 1) {
        const unsigned short* zb = zc + (size_t)(n0 + lr) * KZ + kw + lk * 8;
        f32x4 acc[4][2];
#pragma unroll
        for (int mt = 0; mt < 4; ++mt)
#pragma unroll
          for (int nt = 0; nt < 2; ++nt) acc[mt][nt] = (f32x4){0.f, 0.f, 0.f, 0.f};
#pragma unroll
        for (int kc = 0; kc < 4; ++kc)
#pragma unroll
          for (int nt = 0; nt < 2; ++nt) {
            const bf16x8 b = *(const bf16x8*)(zb + nt * (16 * KZ) + kc * 32);
#pragma unroll
            for (int mt = 0; mt < 4; ++mt)
              acc[mt][nt] = __builtin_amdgcn_mfma_f32_16x16x32_bf16(A[mt][kc], b, acc[mt][nt], 0, 0, 0);
          }
        float* op = out + (size_t)(t - 1) * (WID * NB);
#pragma unroll
        for (int hf = 0; hf < 2; ++hf) {
#pragma unroll
          for (int mp = 0; mp < 2; ++mp) {
            const int mt = hf * 2 + mp;
#pragma unroll
            for (int nt = 0; nt < 2; ++nt)
              *(f32x4*)&Pw[(nt * 16 + lr) * PSTR + mp * 16 + lk * 4] = acc[mt][nt];
          }
          __syncthreads();
          f32x2 s = {0.f, 0.f};
#pragma unroll
          for (int ww = 0; ww < 8; ++ww)
            s += *(const f32x2*)&P[ww * PWSZ + lcol * PSTR + r2];
          s += bias[hf];
          const int row = m0 + hf * 32 + r2;
          op[(size_t)(row + 0) * NB + n0 + lcol] = sigm(s[0]);
          op[(size_t)(row + 1) * NB + n0 + lcol] = sigm(s[1]);
          if (hf == 0) __syncthreads();
        }
      }
      slice_bar(bar, 32u * (unsigned)(t + 1));
    }

  } else {
    // ================= x-transpose role =================
    const int xi = wg - 192;                // 0..63
    const int i0 = (xi >> 3) * 64;          // input-feature block
    const int b0 = (xi & 7) * 32;           // batch block = slice columns (wg&7 preserved)
    const int c = tid & 31, rb = tid >> 5;  // col within block, row-quad 0..15
    for (int t = 0; t <= T_STEPS; ++t) {
      unsigned short* zn = zT + (size_t)((t + 1) & 1) * ZSZ;
      if (t < T_STEPS - 1) {
        const float* xp = xs + (size_t)(t + 1) * (INP * NB) + (size_t)(i0 + rb * 4) * NB + b0 + c;
        ushort4v o;
#pragma unroll
        for (int j = 0; j < 4; ++j) o[j] = f2bf(xp[(size_t)j * NB]);
        *(ushort4v*)(zn + (size_t)(b0 + c) * KZ + HID + i0 + rb * 4) = o;
      }
      slice_bar(bar, 32u * (unsigned)(t + 1));
    }
  }
}

// ---------------- host launch ----------------
extern "C" void kernel_launch(void* const* d_in, const int* in_sizes, int n_in,
                              void* d_out, int out_size, void* d_ws, size_t ws_size,
                              hipStream_t stream) {
  (void)in_sizes; (void)n_in; (void)out_size; (void)ws_size;
  const float* xs  = (const float*)d_in[0];
  const float* W_h = (const float*)d_in[1];
  const float* b_h = (const float*)d_in[2];
  const float* W_y = (const float*)d_in[3];
  const float* b_y = (const float*)d_in[4];
  const float* h0  = (const float*)d_in[5];
  float* out = (float*)d_out;

  // ws layout: zT bf16 [2][256][1536] | barrier counters (8 slices x 256B)
  unsigned short* zT  = (unsigned short*)d_ws;
  unsigned* bars = (unsigned*)(zT + 2 * (size_t)ZSZ);

  elman_setup<<<dim3(NB), dim3(256), 0, stream>>>(h0, xs, zT, bars);

  void* args[8];
  args[0] = (void*)&xs;  args[1] = (void*)&W_h; args[2] = (void*)&b_h;
  args[3] = (void*)&W_y; args[4] = (void*)&b_y; args[5] = (void*)&zT;
  args[6] = (void*)&out; args[7] = (void*)&bars;
  hipLaunchCooperativeKernel((void*)elman_seq, dim3(256), dim3(512), args, 0u, stream);
}

// Round 4
// 4391.782 us; speedup vs baseline: 4.7880x; 1.8698x over previous
//
#include <hip/hip_runtime.h>
#include <hip/hip_bf16.h>

#define T_STEPS 512
#define INP     512
#define NB      256
#define HID     1024
#define WID     512
#define KZ      1536   // HID + INP
#define ZSZ     (NB * KZ)

typedef short          bf16x8   __attribute__((ext_vector_type(8)));
typedef float          f32x4    __attribute__((ext_vector_type(4)));
typedef float          f32x2    __attribute__((ext_vector_type(2)));
typedef unsigned short ushort8  __attribute__((ext_vector_type(8)));
typedef unsigned short ushort2v __attribute__((ext_vector_type(2)));
typedef unsigned short ushort4v __attribute__((ext_vector_type(4)));
typedef unsigned long long u64;
typedef u64            u64x2    __attribute__((ext_vector_type(2)));

__device__ __forceinline__ unsigned short f2bf(float x) {
  __hip_bfloat16 h = __float2bfloat16(x);
  return __builtin_bit_cast(unsigned short, h);
}
__device__ __forceinline__ float sigm(float x) { return 1.0f / (1.0f + __expf(-x)); }

// ---- coherence-point (LLC) resident accesses for the z ping-pong buffer ----
// Relaxed agent-scope atomics compile to sc0|sc1 loads/stores: they bypass the
// non-coherent L1/L2 and read/write the LLC directly -> NO buffer_wbl2/buffer_inv
// cache maintenance is ever needed in the phase loop.
__device__ __forceinline__ bf16x8 zld16(const unsigned short* p) {
  u64x2 v;
  v.x = __hip_atomic_load((const u64*)p,       __ATOMIC_RELAXED, __HIP_MEMORY_SCOPE_AGENT);
  v.y = __hip_atomic_load((const u64*)(p + 4), __ATOMIC_RELAXED, __HIP_MEMORY_SCOPE_AGENT);
  return __builtin_bit_cast(bf16x8, v);
}
__device__ __forceinline__ void zst4(unsigned short* p, ushort2v v) {
  __hip_atomic_store((unsigned*)p, __builtin_bit_cast(unsigned, v),
                     __ATOMIC_RELAXED, __HIP_MEMORY_SCOPE_AGENT);
}
__device__ __forceinline__ void zst8(unsigned short* p, ushort4v v) {
  __hip_atomic_store((u64*)p, __builtin_bit_cast(u64, v),
                     __ATOMIC_RELAXED, __HIP_MEMORY_SCOPE_AGENT);
}

// ---------------- setup: init z[0] = [h0 tiled ; x_0 transposed], zero barriers ----------
__global__ void elman_setup(const float* __restrict__ h0, const float* __restrict__ xs,
                            unsigned short* __restrict__ zT, unsigned* __restrict__ bars) {
  const int b = blockIdx.x;   // batch column 0..255
  if (b == 0) {
    for (int j = threadIdx.x; j < 512; j += blockDim.x) bars[j] = 0u;
  }
  for (int k = threadIdx.x; k < KZ; k += blockDim.x) {
    const float v = (k < HID) ? h0[k] : xs[(size_t)(k - HID) * NB + b];
    zT[(size_t)b * KZ + k] = f2bf(v);
  }
}

// ---------------- per-slice ticket barrier (no cache maintenance) ----------------
// All z traffic is LLC-resident (see above), so release = drain vmcnt (stores are
// acked from the coherence point) and acquire = nothing (loads bypass caches).
__device__ __forceinline__ void slice_bar(unsigned* bar, unsigned tgt) {
  asm volatile("s_waitcnt vmcnt(0)" ::: "memory");  // own z-stores at LLC
  __syncthreads();                                  // everyone's stores drained
  if (threadIdx.x == 0) {
    __hip_atomic_fetch_add(bar, 1u, __ATOMIC_RELAXED, __HIP_MEMORY_SCOPE_AGENT);
    while (__hip_atomic_load(bar, __ATOMIC_RELAXED, __HIP_MEMORY_SCOPE_AGENT) < tgt)
      __builtin_amdgcn_s_sleep(1);
  }
  __syncthreads();
}

// LDS partial-sum buffer: 8 waves x [32 cols][stride 36 words (32 rows + 4 pad)]
#define PSTR 36
#define PWSZ (32 * PSTR)

// ---------------- persistent sequential kernel ----------------
// 256 WGs x 512 threads (8 waves), 1 WG/CU. slice = wg & 7 (group of 32 WGs):
//   16 h-WGs : h_{t+1} = sigm(Wh @ z_t + bh)   (t < T)      tile 64m x 32n, K-split 8
//    8 y-WGs : y_{t-1} = sigm(Wy @ h_t + by)   (t >= 1)     tile 64m x 32n, K-split 8
//    8 x-WGs : transpose x_{t+1} -> z_{t+1}    (t < T-1)
// Weights live in VGPRs for the whole loop.
__global__ void __launch_bounds__(512, 2) elman_seq(
    const float* __restrict__ xs,
    const float* __restrict__ Wh, const float* __restrict__ bh,
    const float* __restrict__ Wy, const float* __restrict__ by,
    unsigned short* __restrict__ zT, float* __restrict__ out,
    unsigned* __restrict__ bars) {
  __shared__ float P[8 * PWSZ];
  const int wg = blockIdx.x, tid = threadIdx.x;
  const int w = tid >> 6, lane = tid & 63;
  const int lr = lane & 15, lk = lane >> 4;
  unsigned* bar = bars + (wg & 7) * 64;    // one cacheline per slice

  if (wg < 128) {
    // ================= h role =================
    const int m0 = (wg >> 3) * 64;          // 16 m-slices
    const int n0 = (wg & 7) * 32;           // slice batch columns
    const int kw = w * 192;                 // this wave's K-slice (6 chunks of 32)
    bf16x8 A[4][6];                         // resident W_h fragments: 96 VGPRs
#pragma unroll
    for (int mt = 0; mt < 4; ++mt)
#pragma unroll
      for (int kc = 0; kc < 6; ++kc) {
        const float* wp = Wh + (size_t)(m0 + mt * 16 + lr) * KZ + kw + kc * 32 + lk * 8;
        const f32x4 f0 = *(const f32x4*)wp;
        const f32x4 f1 = *(const f32x4*)(wp + 4);
        ushort8 a;
#pragma unroll
        for (int e = 0; e < 4; ++e) { a[e] = f2bf(f0[e]); a[4 + e] = f2bf(f1[e]); }
        A[mt][kc] = __builtin_bit_cast(bf16x8, a);
      }
    const int lcol = tid >> 4;              // reduction role: col 0..31
    const int r2 = (tid & 15) * 2;          // row pair within 32-row half
    f32x2 bias[2];
#pragma unroll
    for (int hf = 0; hf < 2; ++hf) bias[hf] = *(const f32x2*)&bh[m0 + hf * 32 + r2];
    float* Pw = P + w * PWSZ;

    for (int t = 0; t <= T_STEPS; ++t) {
      const unsigned short* zc = zT + (size_t)(t & 1) * ZSZ;
      unsigned short* zn = zT + (size_t)((t + 1) & 1) * ZSZ;
      if (t < T_STEPS) {
        const unsigned short* zb = zc + (size_t)(n0 + lr) * KZ + kw + lk * 8;
        f32x4 acc[4][2];
#pragma unroll
        for (int mt = 0; mt < 4; ++mt)
#pragma unroll
          for (int nt = 0; nt < 2; ++nt) acc[mt][nt] = (f32x4){0.f, 0.f, 0.f, 0.f};
#pragma unroll
        for (int kc = 0; kc < 6; ++kc)
#pragma unroll
          for (int nt = 0; nt < 2; ++nt) {
            const bf16x8 b = zld16(zb + nt * (16 * KZ) + kc * 32);
#pragma unroll
            for (int mt = 0; mt < 4; ++mt)
              acc[mt][nt] = __builtin_amdgcn_mfma_f32_16x16x32_bf16(A[mt][kc], b, acc[mt][nt], 0, 0, 0);
          }
        // two-pass cross-wave K reduction (32-row halves) through 36 KiB LDS
#pragma unroll
        for (int hf = 0; hf < 2; ++hf) {
#pragma unroll
          for (int mp = 0; mp < 2; ++mp) {
            const int mt = hf * 2 + mp;
#pragma unroll
            for (int nt = 0; nt < 2; ++nt)
              *(f32x4*)&Pw[(nt * 16 + lr) * PSTR + mp * 16 + lk * 4] = acc[mt][nt];
          }
          __syncthreads();
          f32x2 s = {0.f, 0.f};
#pragma unroll
          for (int ww = 0; ww < 8; ++ww)
            s += *(const f32x2*)&P[ww * PWSZ + lcol * PSTR + r2];
          s += bias[hf];
          ushort2v o2;
          o2[0] = f2bf(sigm(s[0]));
          o2[1] = f2bf(sigm(s[1]));
          zst4(zn + (size_t)(n0 + lcol) * KZ + m0 + hf * 32 + r2, o2);
          if (hf == 0) __syncthreads();   // reads done before pass-2 writes
        }
      }
      slice_bar(bar, 32u * (unsigned)(t + 1));
    }

  } else if (wg < 192) {
    // ================= y role =================
    const int idx = wg - 128;
    const int m0 = (idx >> 3) * 64;         // 8 m-slices
    const int n0 = (idx & 7) * 32;          // same slice as h role (wg&7 preserved)
    const int kw = w * 128;                 // K-slice: 4 chunks of 32 (K = HID)
    bf16x8 A[4][4];                         // resident W_y fragments: 64 VGPRs
#pragma unroll
    for (int mt = 0; mt < 4; ++mt)
#pragma unroll
      for (int kc = 0; kc < 4; ++kc) {
        const float* wp = Wy + (size_t)(m0 + mt * 16 + lr) * HID + kw + kc * 32 + lk * 8;
        const f32x4 f0 = *(const f32x4*)wp;
        const f32x4 f1 = *(const f32x4*)(wp + 4);
        ushort8 a;
#pragma unroll
        for (int e = 0; e < 4; ++e) { a[e] = f2bf(f0[e]); a[4 + e] = f2bf(f1[e]); }
        A[mt][kc] = __builtin_bit_cast(bf16x8, a);
      }
    const int lcol = tid & 31;              // reduction role: col (coalesced f32 stores)
    const int r2 = (tid >> 5) * 2;          // row pair within 32-row half
    f32x2 bias[2];
#pragma unroll
    for (int hf = 0; hf < 2; ++hf) bias[hf] = *(const f32x2*)&by[m0 + hf * 32 + r2];
    float* Pw = P + w * PWSZ;

    for (int t = 0; t <= T_STEPS; ++t) {
      const unsigned short* zc = zT + (size_t)(t & 1) * ZSZ;
      if (t >= 1) {
        const unsigned short* zb = zc + (size_t)(n0 + lr) * KZ + kw + lk * 8;
        f32x4 acc[4][2];
#pragma unroll
        for (int mt = 0; mt < 4; ++mt)
#pragma unroll
          for (int nt = 0; nt < 2; ++nt) acc[mt][nt] = (f32x4){0.f, 0.f, 0.f, 0.f};
#pragma unroll
        for (int kc = 0; kc < 4; ++kc)
#pragma unroll
          for (int nt = 0; nt < 2; ++nt) {
            const bf16x8 b = zld16(zb + nt * (16 * KZ) + kc * 32);
#pragma unroll
            for (int mt = 0; mt < 4; ++mt)
              acc[mt][nt] = __builtin_amdgcn_mfma_f32_16x16x32_bf16(A[mt][kc], b, acc[mt][nt], 0, 0, 0);
          }
        float* op = out + (size_t)(t - 1) * (WID * NB);
#pragma unroll
        for (int hf = 0; hf < 2; ++hf) {
#pragma unroll
          for (int mp = 0; mp < 2; ++mp) {
            const int mt = hf * 2 + mp;
#pragma unroll
            for (int nt = 0; nt < 2; ++nt)
              *(f32x4*)&Pw[(nt * 16 + lr) * PSTR + mp * 16 + lk * 4] = acc[mt][nt];
          }
          __syncthreads();
          f32x2 s = {0.f, 0.f};
#pragma unroll
          for (int ww = 0; ww < 8; ++ww)
            s += *(const f32x2*)&P[ww * PWSZ + lcol * PSTR + r2];
          s += bias[hf];
          const int row = m0 + hf * 32 + r2;
          op[(size_t)(row + 0) * NB + n0 + lcol] = sigm(s[0]);  // normal stores: flushed at kernel end
          op[(size_t)(row + 1) * NB + n0 + lcol] = sigm(s[1]);
          if (hf == 0) __syncthreads();
        }
      }
      slice_bar(bar, 32u * (unsigned)(t + 1));
    }

  } else {
    // ================= x-transpose role =================
    const int xi = wg - 192;                // 0..63
    const int i0 = (xi >> 3) * 64;          // input-feature block
    const int b0 = (xi & 7) * 32;           // batch block = slice columns (wg&7 preserved)
    const int c = tid & 31, rb = tid >> 5;  // col within block, row-quad 0..15
    for (int t = 0; t <= T_STEPS; ++t) {
      unsigned short* zn = zT + (size_t)((t + 1) & 1) * ZSZ;
      if (t < T_STEPS - 1) {
        const float* xp = xs + (size_t)(t + 1) * (INP * NB) + (size_t)(i0 + rb * 4) * NB + b0 + c;
        ushort4v o;
#pragma unroll
        for (int j = 0; j < 4; ++j) o[j] = f2bf(xp[(size_t)j * NB]);
        zst8(zn + (size_t)(b0 + c) * KZ + HID + i0 + rb * 4, o);
      }
      slice_bar(bar, 32u * (unsigned)(t + 1));
    }
  }
}

// ---------------- host launch ----------------
extern "C" void kernel_launch(void* const* d_in, const int* in_sizes, int n_in,
                              void* d_out, int out_size, void* d_ws, size_t ws_size,
                              hipStream_t stream) {
  (void)in_sizes; (void)n_in; (void)out_size; (void)ws_size;
  const float* xs  = (const float*)d_in[0];
  const float* W_h = (const float*)d_in[1];
  const float* b_h = (const float*)d_in[2];
  const float* W_y = (const float*)d_in[3];
  const float* b_y = (const float*)d_in[4];
  const float* h0  = (const float*)d_in[5];
  float* out = (float*)d_out;

  // ws layout: zT bf16 [2][256][1536] | barrier counters (8 slices x 256B)
  unsigned short* zT  = (unsigned short*)d_ws;
  unsigned* bars = (unsigned*)(zT + 2 * (size_t)ZSZ);

  elman_setup<<<dim3(NB), dim3(256), 0, stream>>>(h0, xs, zT, bars);

  void* args[8];
  args[0] = (void*)&xs;  args[1] = (void*)&W_h; args[2] = (void*)&b_h;
  args[3] = (void*)&W_y; args[4] = (void*)&b_y; args[5] = (void*)&zT;
  args[6] = (void*)&out; args[7] = (void*)&bars;
  hipLaunchCooperativeKernel((void*)elman_seq, dim3(256), dim3(512), args, 0u, stream);
}